// Round 1
// baseline (130.591 us; speedup 1.0000x reference)
//
#include <hip/hip_runtime.h>
#include <stdint.h>

#define NCLS   80
#define HWTOT  21824
#define MBOX   100

// flat f32 output layout (return-order concat)
#define REG_OFF 28633088ull   // 16*21824*82
#define IND_OFF 30728192ull   // + 16*21824*6
#define NB_OFF  31077376ull   // + 16*21824

__global__ __launch_bounds__(256)
void sapd_targets(const float* __restrict__ gt, float* __restrict__ out)
{
    const int tid = threadIdx.x;
    const int c   = blockIdx.x;   // chunk id within batch, 0..85
    const int b   = blockIdx.y;   // batch 0..15

    // chunk -> (level, pixel0, level base). Chunks never cross level bounds.
    int lvl, pix0, base;
    if      (c < 64) { lvl = 0; pix0 = c << 8;        base = 0;     }
    else if (c < 80) { lvl = 1; pix0 = (c - 64) << 8; base = 16384; }
    else if (c < 84) { lvl = 2; pix0 = (c - 80) << 8; base = 20480; }
    else if (c < 85) { lvl = 3; pix0 = 0;             base = 21504; }
    else             { lvl = 4; pix0 = 0;             base = 21760; }

    const int   l2fw   = 7 - lvl;        // fw: 128,64,32,16,8
    const int   fw     = 1 << l2fw;
    const float fs     = (float)(8 << lvl);
    const int   chunkN = (lvl == 4) ? 64 : 256;

    __shared__ uint32_t sBB[MBOX];     // packed shrunk bounds (u8 x4)
    __shared__ float    sArea[MBOX];
    __shared__ int      sValid[MBOX];
    __shared__ float4   sBox[MBOX];    // original image-space coords
    __shared__ int      sLab[MBOX];
    __shared__ float2   sCull[MBOX];   // {bounds as float bits, area}
    __shared__ int      sOrig[MBOX];
    __shared__ int      sN;
    __shared__ uint32_t rMeta[256];    // label | (pos<<8)
    __shared__ float    rSoft[256];
    __shared__ float    rReg[256 * 4];

    // ---- phase 1: per-box precompute (level-specific) ----
    if (tid < MBOX) {
        const float* g = gt + ((size_t)b * MBOX + tid) * 5;
        float x1 = g[0], y1 = g[1], x2 = g[2], y2 = g[3], lab = g[4];
        int valid = (fabsf(x1) + fabsf(y1) + fabsf(x2) + fabsf(y2)) > 0.0f;
        float area = (x2 - x1) * (y2 - y1);
        float bx1 = x1 / fs, by1 = y1 / fs, bx2 = x2 / fs, by2 = y2 / fs;
        float cx = (bx1 + bx2) * 0.5f, cy = (by1 + by2) * 0.5f;
        float hw = (bx2 - bx1) * 0.5f * 0.2f, hh = (by2 - by1) * 0.5f * 0.2f;
        float px1 = fmaxf(floorf(cx - hw), 0.0f);
        float py1 = fmaxf(floorf(cy - hh), 0.0f);
        float px2 = fminf(ceilf(cx + hw), (float)fw);
        float py2 = fminf(ceilf(cy + hh), (float)fw);
        uint32_t bb = (uint32_t)px1 | ((uint32_t)py1 << 8) |
                      ((uint32_t)px2 << 16) | ((uint32_t)py2 << 24);
        sBB[tid]    = bb;
        sArea[tid]  = area;
        sValid[tid] = valid;
        sBox[tid]   = make_float4(x1, y1, x2, y2);
        sLab[tid]   = (int)lab;
    }
    __syncthreads();

    // num_boxes: lvl-4 blocks (one per batch), idle thread 64
    if (lvl == 4 && tid == 64) {
        int cnt = 0;
        for (int m = 0; m < MBOX; ++m) cnt += sValid[m];
        out[NB_OFF + b] = (float)cnt;
    }

    // ---- phase 2: wave-0 order-preserving row-band cull ----
    if (tid < 64) {
        const int lane = tid;
        const int ry0 = pix0 >> l2fw;
        const int ry1 = ry0 + (chunkN >> l2fw);
        int n0;
        {
            int m = lane;   // m < 64 < MBOX always
            uint32_t bb = sBB[m];
            int ix1 = bb & 255, iy1 = (bb >> 8) & 255, ix2 = (bb >> 16) & 255, iy2 = bb >> 24;
            bool pred = sValid[m] && (ix2 > ix1) && (iy2 > ry0) && (iy1 < ry1);
            unsigned long long mk = __ballot(pred);
            n0 = __popcll(mk);
            if (pred) {
                int p = __popcll(mk & ((1ull << lane) - 1ull));
                sCull[p] = make_float2(__uint_as_float(bb), sArea[m]);
                sOrig[p] = m;
            }
        }
        {
            int m = 64 + lane;
            bool pred = false;
            uint32_t bb = 0;
            float ar = 0.0f;
            if (m < MBOX) {
                bb = sBB[m]; ar = sArea[m];
                int ix1 = bb & 255, iy1 = (bb >> 8) & 255, ix2 = (bb >> 16) & 255, iy2 = bb >> 24;
                pred = sValid[m] && (ix2 > ix1) && (iy2 > ry0) && (iy1 < ry1);
            }
            unsigned long long mk = __ballot(pred);
            if (pred) {
                int p = n0 + __popcll(mk & ((1ull << lane) - 1ull));
                sCull[p] = make_float2(__uint_as_float(bb), ar);
                sOrig[p] = m;
            }
            if (lane == 0) sN = n0 + __popcll(mk);
        }
    }
    __syncthreads();

    // ---- phase 3: per-pixel argmin + target math ----
    if (tid < chunkN) {
        const int p  = pix0 + tid;
        const int px = p & (fw - 1);
        const int py = p >> l2fw;
        float bestA = 1e30f; int bestI = -1;
        const int n = sN;
        for (int i = 0; i < n; ++i) {
            float2 e = sCull[i];
            uint32_t bb = __float_as_uint(e.x);
            int x1 = bb & 255, y1 = (bb >> 8) & 255, x2 = (bb >> 16) & 255, y2 = bb >> 24;
            bool hit = (px >= x1) & (px < x2) & (py >= y1) & (py < y2);
            bool upd = hit & (e.y < bestA);   // strict < keeps first (orig-order) on ties
            bestA = upd ? e.y : bestA;
            bestI = upd ? i : bestI;
        }
        bool pos = bestI >= 0;
        int orig = pos ? sOrig[bestI] : 0;
        float4 bx = sBox[orig];
        float sx = ((float)px + 0.5f) * fs;
        float sy = ((float)py + 0.5f) * fs;
        float l  = sx - bx.x, t = sy - bx.y, r = bx.z - sx, bt = bx.w - sy;
        float inv4s = 1.0f / (4.0f * fs);   // power of two: exact vs reference divide
        float posf  = pos ? 1.0f : 0.0f;
        const float eps = 1e-6f;
        float a1 = fminf(l, r) / fmaxf(fmaxf(l, r), eps);
        a1 = fminf(fmaxf(a1, 0.0f), 1.0f);
        float a2 = fminf(t, bt) / fmaxf(fmaxf(t, bt), eps);
        a2 = fminf(fmaxf(a2, 0.0f), 1.0f);
        float cent = sqrtf(a1 * a2);
        float soft = pos ? cent : 1.0f;
        rMeta[tid] = (uint32_t)sLab[orig] | (pos ? 0x100u : 0u);
        rSoft[tid] = soft;
        rReg[tid * 4 + 0] = l  * inv4s * posf;
        rReg[tid * 4 + 1] = t  * inv4s * posf;
        rReg[tid * 4 + 2] = r  * inv4s * posf;
        rReg[tid * 4 + 3] = bt * inv4s * posf;
        out[IND_OFF + (size_t)b * HWTOT + base + p] = pos ? (float)orig : -1.0f;
    }
    __syncthreads();

    // ---- phase 4: coalesced output writes ----
    const size_t rowbase = (size_t)b * HWTOT + base + pix0;
    {
        float* oc = out + rowbase * 82;
        const int n = chunkN * 82;
        for (int i = tid; i < n; i += 256) {
            unsigned row = (unsigned)i / 82u;
            unsigned col = (unsigned)i - row * 82u;
            uint32_t mm = rMeta[row];
            float posf = (mm & 0x100u) ? 1.0f : 0.0f;
            float v;
            if (col < 80u)       v = (col == (mm & 0xffu)) ? posf : 0.0f;
            else if (col == 80u) v = rSoft[row];
            else                 v = posf;
            oc[i] = v;
        }
    }
    {
        float* orr = out + REG_OFF + rowbase * 6;
        const int n = chunkN * 6;
        for (int i = tid; i < n; i += 256) {
            unsigned row = (unsigned)i / 6u;
            unsigned col = (unsigned)i - row * 6u;
            float v;
            if (col < 4u)       v = rReg[row * 4 + col];
            else if (col == 4u) v = rSoft[row];
            else                v = (rMeta[row] & 0x100u) ? 1.0f : 0.0f;
            orr[i] = v;
        }
    }
}

extern "C" void kernel_launch(void* const* d_in, const int* in_sizes, int n_in,
                              void* d_out, int out_size, void* d_ws, size_t ws_size,
                              hipStream_t stream)
{
    const float* gt = (const float*)d_in[0];
    float* out = (float*)d_out;
    sapd_targets<<<dim3(86, 16), 256, 0, stream>>>(gt, out);
}

// Round 2
// 127.755 us; speedup vs baseline: 1.0222x; 1.0222x over previous
//
#include <hip/hip_runtime.h>
#include <stdint.h>

#define NCLS   80
#define HWTOT  21824
#define MBOX   100

// flat f32 output layout (return-order concat)
#define REG_OFF 28633088ull   // 16*21824*82
#define IND_OFF 30728192ull   // + 16*21824*6
#define NB_OFF  31077376ull   // + 16*21824

__global__ __launch_bounds__(256)
void sapd_targets(const float* __restrict__ gt, float* __restrict__ out)
{
    const int tid = threadIdx.x;
    const int c   = blockIdx.x;   // chunk id within batch, 0..85
    const int b   = blockIdx.y;   // batch 0..15

    // chunk -> (level, pixel0, level base). Chunks never cross level bounds.
    int lvl, pix0, base;
    if      (c < 64) { lvl = 0; pix0 = c << 8;        base = 0;     }
    else if (c < 80) { lvl = 1; pix0 = (c - 64) << 8; base = 16384; }
    else if (c < 84) { lvl = 2; pix0 = (c - 80) << 8; base = 20480; }
    else if (c < 85) { lvl = 3; pix0 = 0;             base = 21504; }
    else             { lvl = 4; pix0 = 0;             base = 21760; }

    const int   l2fw   = 7 - lvl;        // fw: 128,64,32,16,8
    const int   fw     = 1 << l2fw;
    const float fs     = (float)(8 << lvl);
    const int   chunkN = (lvl == 4) ? 64 : 256;

    const size_t rowbase = (size_t)b * HWTOT + base + pix0;  // always even
    float* const ocls = out + rowbase * 82;                  // 16B-aligned

    // ---- pass A: dependency-free zero-fill of the cls region (92% of bytes).
    // Issued first so the store stream overlaps phases 1-3 entirely.
    {
        const float4 z = make_float4(0.f, 0.f, 0.f, 0.f);
        float4* o4 = (float4*)ocls;
        const int n4 = (chunkN * 82) >> 2;   // 5248 or 1312
        for (int i = tid; i < n4; i += 256) o4[i] = z;
    }

    __shared__ uint32_t sBB[MBOX];     // packed shrunk bounds (u8 x4)
    __shared__ float    sArea[MBOX];
    __shared__ int      sValid[MBOX];
    __shared__ float4   sBox[MBOX];    // original image-space coords
    __shared__ int      sLab[MBOX];
    __shared__ float2   sCull[MBOX];   // {bounds as float bits, area}
    __shared__ int      sOrig[MBOX];
    __shared__ int      sN;
    __shared__ float2   sSP[256];      // {soft, posf} per pixel
    __shared__ float    rReg[256 * 4];

    // ---- phase 1: per-box precompute (level-specific) ----
    if (tid < MBOX) {
        const float* g = gt + ((size_t)b * MBOX + tid) * 5;
        float x1 = g[0], y1 = g[1], x2 = g[2], y2 = g[3], lab = g[4];
        int valid = (fabsf(x1) + fabsf(y1) + fabsf(x2) + fabsf(y2)) > 0.0f;
        float area = (x2 - x1) * (y2 - y1);
        float bx1 = x1 / fs, by1 = y1 / fs, bx2 = x2 / fs, by2 = y2 / fs;
        float cx = (bx1 + bx2) * 0.5f, cy = (by1 + by2) * 0.5f;
        float hw = (bx2 - bx1) * 0.5f * 0.2f, hh = (by2 - by1) * 0.5f * 0.2f;
        float px1 = fmaxf(floorf(cx - hw), 0.0f);
        float py1 = fmaxf(floorf(cy - hh), 0.0f);
        float px2 = fminf(ceilf(cx + hw), (float)fw);
        float py2 = fminf(ceilf(cy + hh), (float)fw);
        uint32_t bb = (uint32_t)px1 | ((uint32_t)py1 << 8) |
                      ((uint32_t)px2 << 16) | ((uint32_t)py2 << 24);
        sBB[tid]    = bb;
        sArea[tid]  = area;
        sValid[tid] = valid;
        sBox[tid]   = make_float4(x1, y1, x2, y2);
        sLab[tid]   = (int)lab;
    }
    __syncthreads();

    // num_boxes: lvl-4 blocks (one per batch), thread 64 idle in phase 3
    if (lvl == 4 && tid == 64) {
        int cnt = 0;
        for (int m = 0; m < MBOX; ++m) cnt += sValid[m];
        out[NB_OFF + b] = (float)cnt;
    }

    // ---- phase 2: wave-0 order-preserving row-band cull ----
    if (tid < 64) {
        const int lane = tid;
        const int ry0 = pix0 >> l2fw;
        const int ry1 = ry0 + (chunkN >> l2fw);
        int n0;
        {
            int m = lane;   // m < 64 < MBOX always
            uint32_t bb = sBB[m];
            int ix1 = bb & 255, iy1 = (bb >> 8) & 255, ix2 = (bb >> 16) & 255, iy2 = bb >> 24;
            bool pred = sValid[m] && (ix2 > ix1) && (iy2 > ry0) && (iy1 < ry1);
            unsigned long long mk = __ballot(pred);
            n0 = __popcll(mk);
            if (pred) {
                int p = __popcll(mk & ((1ull << lane) - 1ull));
                sCull[p] = make_float2(__uint_as_float(bb), sArea[m]);
                sOrig[p] = m;
            }
        }
        {
            int m = 64 + lane;
            bool pred = false;
            uint32_t bb = 0;
            float ar = 0.0f;
            if (m < MBOX) {
                bb = sBB[m]; ar = sArea[m];
                int ix1 = bb & 255, iy1 = (bb >> 8) & 255, ix2 = (bb >> 16) & 255, iy2 = bb >> 24;
                pred = sValid[m] && (ix2 > ix1) && (iy2 > ry0) && (iy1 < ry1);
            }
            unsigned long long mk = __ballot(pred);
            if (pred) {
                int p = n0 + __popcll(mk & ((1ull << lane) - 1ull));
                sCull[p] = make_float2(__uint_as_float(bb), ar);
                sOrig[p] = m;
            }
            if (lane == 0) sN = n0 + __popcll(mk);
        }
    }
    __syncthreads();

    // ---- phase 3: per-pixel argmin + target math (results stay in registers) ----
    bool  pos  = false;
    int   lab  = 0;
    float soft = 1.0f, posf = 0.0f;
    if (tid < chunkN) {
        const int p  = pix0 + tid;
        const int px = p & (fw - 1);
        const int py = p >> l2fw;
        float bestA = 1e30f; int bestI = -1;
        const int n = sN;
        for (int i = 0; i < n; ++i) {
            float2 e = sCull[i];
            uint32_t bb = __float_as_uint(e.x);
            int x1 = bb & 255, y1 = (bb >> 8) & 255, x2 = (bb >> 16) & 255, y2 = bb >> 24;
            bool hit = (px >= x1) & (px < x2) & (py >= y1) & (py < y2);
            bool upd = hit & (e.y < bestA);   // strict < keeps first (orig-order) on ties
            bestA = upd ? e.y : bestA;
            bestI = upd ? i : bestI;
        }
        pos = bestI >= 0;
        int orig = pos ? sOrig[bestI] : 0;
        float4 bx = sBox[orig];
        float sx = ((float)px + 0.5f) * fs;
        float sy = ((float)py + 0.5f) * fs;
        float l  = sx - bx.x, t = sy - bx.y, r = bx.z - sx, bt = bx.w - sy;
        float inv4s = 1.0f / (4.0f * fs);   // power of two: exact vs reference divide
        posf  = pos ? 1.0f : 0.0f;
        const float eps = 1e-6f;
        float a1 = fminf(l, r) / fmaxf(fmaxf(l, r), eps);
        a1 = fminf(fmaxf(a1, 0.0f), 1.0f);
        float a2 = fminf(t, bt) / fmaxf(fmaxf(t, bt), eps);
        a2 = fminf(fmaxf(a2, 0.0f), 1.0f);
        float cent = sqrtf(a1 * a2);
        soft = pos ? cent : 1.0f;
        lab  = sLab[orig];
        sSP[tid] = make_float2(soft, posf);
        rReg[tid * 4 + 0] = l  * inv4s * posf;
        rReg[tid * 4 + 1] = t  * inv4s * posf;
        rReg[tid * 4 + 2] = r  * inv4s * posf;
        rReg[tid * 4 + 3] = bt * inv4s * posf;
        out[IND_OFF + rowbase + tid] = pos ? (float)(pos ? sOrig[bestI] : 0) : -1.0f;
    }
    // barrier also orders pass-A zero stores before the pass-B patch stores
    __syncthreads();

    // ---- pass B: per-row cls patch from registers (no LDS round-trip) ----
    if (tid < chunkN) {
        float* row = ocls + tid * 82;
        *(float2*)(row + 80) = make_float2(soft, posf);  // 8B-aligned (row idx even*82+80)
        if (pos) row[lab] = 1.0f;
    }

    // ---- reg output: contiguous float4 fill from LDS ----
    {
        float4* o4 = (float4*)(out + REG_OFF + rowbase * 6);   // 16B-aligned
        const int n4 = (chunkN * 6) >> 2;   // 384 or 96
        for (int i = tid; i < n4; i += 256) {
            int idx = i << 2;
            float v[4];
            #pragma unroll
            for (int k = 0; k < 4; ++k) {
                int id  = idx + k;
                int row = (int)((unsigned)id / 6u);
                int col = id - row * 6;
                float2 sp = sSP[row];
                v[k] = (col < 4) ? rReg[row * 4 + col] : ((col == 4) ? sp.x : sp.y);
            }
            o4[i] = make_float4(v[0], v[1], v[2], v[3]);
        }
    }
}

extern "C" void kernel_launch(void* const* d_in, const int* in_sizes, int n_in,
                              void* d_out, int out_size, void* d_ws, size_t ws_size,
                              hipStream_t stream)
{
    const float* gt = (const float*)d_in[0];
    float* out = (float*)d_out;
    sapd_targets<<<dim3(86, 16), 256, 0, stream>>>(gt, out);
}